// Round 1
// baseline (110.980 us; speedup 1.0000x reference)
//
#include <hip/hip_runtime.h>
#include <hip/hip_bf16.h>
#include <stdint.h>

// RNDiscriminator: B=64, d^2=64 positions, 26 features, g: 52->256->256, f: 256->1
//
// Factorization: h1[i,j] = relu(u'[j] + v[i]) with u' = x@W1[:26]+b1, v = x@W1[26:].
// Dominant cost: sum_{i,j} relu(h1[i,j] @ W2 + b2)  == 34.4 GFLOP bf16 MFMA.

typedef float f32x4 __attribute__((ext_vector_type(4)));
typedef short short8 __attribute__((ext_vector_type(8)));
typedef short short4v __attribute__((ext_vector_type(4)));

__device__ __forceinline__ short bf16_rne(float f) {
    union { float f; uint32_t u; } v; v.f = f;
    uint32_t u = v.u + 0x7FFFu + ((v.u >> 16) & 1u);
    return (short)(u >> 16);
}

// K1: conv 8x8 stride 8 + relu + coord channels -> x[b][pos][26]
__global__ void k1_conv(const float* __restrict__ img, const float* __restrict__ cw,
                        const float* __restrict__ cb, float* __restrict__ x) {
    int b = blockIdx.x >> 2;
    int q = blockIdx.x & 3;
    for (int idx = q * 416 + threadIdx.x; idx < q * 416 + 416; idx += 256) {
        int pos = idx / 26;
        int ch  = idx - pos * 26;
        int r = pos >> 3, c = pos & 7;
        float val;
        if (ch < 24) {
            float s = cb[ch];
            #pragma unroll
            for (int ci = 0; ci < 3; ++ci)
                #pragma unroll
                for (int kr = 0; kr < 8; ++kr) {
                    const float* ip = img + ((b * 3 + ci) * 64 + r * 8 + kr) * 64 + c * 8;
                    const float* wp = cw + ((ch * 3 + ci) * 8 + kr) * 8;
                    #pragma unroll
                    for (int kc = 0; kc < 8; ++kc) s += ip[kc] * wp[kc];
                }
            val = fmaxf(s, 0.f);
        } else if (ch == 24) {
            val = -1.f + (2.f / 7.f) * (float)c;   // cx varies along columns
        } else {
            val = -1.f + (2.f / 7.f) * (float)r;   // cy varies along rows
        }
        x[(b * 64 + pos) * 26 + ch] = val;
    }
}

// K2: u'[bj][c] = sum_k x[bj][k]*W1[k][c] + b1[c]   (uv=0)
//     v [bj][c] = sum_k x[bj][k]*W1[26+k][c]        (uv=1)
__global__ void k2_uv(const float* __restrict__ x, const float* __restrict__ w1,
                      const float* __restrict__ b1, float* __restrict__ u,
                      float* __restrict__ v) {
    int bj = blockIdx.x & 4095;
    int uv = blockIdx.x >> 12;
    int c = threadIdx.x;
    const float* xr = x + bj * 26;
    const float* w  = w1 + uv * 26 * 256;
    float s = uv ? 0.f : b1[c];
    #pragma unroll
    for (int k = 0; k < 26; ++k) s += xr[k] * w[k * 256 + c];
    (uv ? v : u)[bj * 256 + c] = s;
}

// K2b: W2t[n][k] = bf16(W2[k][n])  (transposed so B-fragments are 16B contiguous in k)
__global__ void k2b_w2t(const float* __restrict__ w2, short* __restrict__ w2t) {
    int n = blockIdx.x, k = threadIdx.x;
    w2t[n * 256 + k] = bf16_rne(w2[k * 256 + n]);
}

// K3: per block (b,i): A = relu(u'[j]+v[i]) (64x256 bf16 in LDS, XOR-swizzled),
//     C = A @ W2 (MFMA 16x16x32), epilogue relu(C+b2) column-summed -> part[blk][256]
__global__ __launch_bounds__(256, 2) void k3_pairs(
        const float* __restrict__ u, const float* __restrict__ v,
        const short* __restrict__ w2t, const float* __restrict__ b2,
        float* __restrict__ part) {
    __shared__ short h1s[64 * 256];   // 32 KB
    int blk = blockIdx.x;
    int b = blk >> 6, i = blk & 63;
    int t = threadIdx.x;

    // ---- stage h1 = relu(u'[j] + v[i]) as bf16, swizzled ----
    const float* vp = v + (b * 64 + i) * 256;
    int kq = (t & 63) * 4;        // k base (4 elems per thread per row)
    int tg = t >> 6;              // row subgroup 0..3
    #pragma unroll
    for (int rr = 0; rr < 16; ++rr) {
        int row = rr * 4 + tg;
        float4 uu = *(const float4*)(u + (b * 64 + row) * 256 + kq);
        float4 vv = *(const float4*)(vp + kq);
        short4v h;
        h.x = bf16_rne(fmaxf(uu.x + vv.x, 0.f));
        h.y = bf16_rne(fmaxf(uu.y + vv.y, 0.f));
        h.z = bf16_rne(fmaxf(uu.z + vv.z, 0.f));
        h.w = bf16_rne(fmaxf(uu.w + vv.w, 0.f));
        int byte = row * 512 + kq * 2;
        byte ^= (row & 7) << 4;   // XOR swizzle (16B slots across banks)
        *(short4v*)((char*)h1s + byte) = h;
    }
    __syncthreads();

    // ---- GEMM: each wave computes rows 0..63 x cols [wv*64, wv*64+64) ----
    int lane = t & 63, wv = t >> 6;
    int n0 = wv * 64;
    int lr = lane & 15, lg = lane >> 4;

    f32x4 zero = {0.f, 0.f, 0.f, 0.f};
    f32x4 acc[4][4];
    #pragma unroll
    for (int mi = 0; mi < 4; ++mi)
        #pragma unroll
        for (int ni = 0; ni < 4; ++ni) acc[mi][ni] = zero;

    #pragma unroll
    for (int ks = 0; ks < 8; ++ks) {
        int kb = ks * 32 + lg * 8;
        short8 a[4], bb[4];
        #pragma unroll
        for (int mi = 0; mi < 4; ++mi) {
            int row = mi * 16 + lr;
            int byte = row * 512 + kb * 2;
            byte ^= (row & 7) << 4;
            a[mi] = *(const short8*)((const char*)h1s + byte);
        }
        #pragma unroll
        for (int ni = 0; ni < 4; ++ni) {
            int col = n0 + ni * 16 + lr;
            bb[ni] = *(const short8*)(w2t + col * 256 + kb);  // 16B contiguous
        }
        #pragma unroll
        for (int mi = 0; mi < 4; ++mi)
            #pragma unroll
            for (int ni = 0; ni < 4; ++ni)
                acc[mi][ni] = __builtin_amdgcn_mfma_f32_16x16x32_bf16(
                    a[mi], bb[ni], acc[mi][ni], 0, 0, 0);
    }

    // ---- epilogue: relu(C + b2) column-sum over 64 rows ----
    #pragma unroll
    for (int ni = 0; ni < 4; ++ni) {
        int col = n0 + ni * 16 + lr;
        float bias = b2[col];
        float s = 0.f;
        #pragma unroll
        for (int mi = 0; mi < 4; ++mi)
            #pragma unroll
            for (int r = 0; r < 4; ++r)
                s += fmaxf(acc[mi][ni][r] + bias, 0.f);
        s += __shfl_xor(s, 16);
        s += __shfl_xor(s, 32);
        if (lane < 16) part[blk * 256 + col] = s;
    }
}

// K4: pooled[b][c] = sum_i part[b*64+i][c]
__global__ void k4_pool(const float* __restrict__ part, float* __restrict__ pooled) {
    int b = blockIdx.x, t = threadIdx.x;
    float s = 0.f;
    for (int i = 0; i < 64; ++i) s += part[(b * 64 + i) * 256 + t];
    pooled[b * 256 + t] = s;
}

// K5: f-head: out[b] = relu(pooled@fw1+fb1) @ fw2 + fb2
__global__ void k5_head(const float* __restrict__ pooled, const float* __restrict__ fw1,
                        const float* __restrict__ fb1, const float* __restrict__ fw2,
                        const float* __restrict__ fb2, float* __restrict__ out) {
    __shared__ float P[256];
    __shared__ float wsum[4];
    int b = blockIdx.x, t = threadIdx.x;
    P[t] = pooled[b * 256 + t];
    __syncthreads();
    float s = fb1[t];
    for (int k = 0; k < 256; ++k) s += P[k] * fw1[k * 256 + t];
    float h = fmaxf(s, 0.f);
    float p = h * fw2[t];
    #pragma unroll
    for (int off = 32; off >= 1; off >>= 1) p += __shfl_xor(p, off);
    if ((t & 63) == 0) wsum[t >> 6] = p;
    __syncthreads();
    if (t == 0) out[b] = wsum[0] + wsum[1] + wsum[2] + wsum[3] + fb2[0];
}

extern "C" void kernel_launch(void* const* d_in, const int* in_sizes, int n_in,
                              void* d_out, int out_size, void* d_ws, size_t ws_size,
                              hipStream_t stream) {
    const float* image  = (const float*)d_in[0];
    const float* conv_w = (const float*)d_in[1];
    const float* conv_b = (const float*)d_in[2];
    const float* g_w1   = (const float*)d_in[3];
    const float* g_b1   = (const float*)d_in[4];
    const float* g_w2   = (const float*)d_in[5];
    const float* g_b2   = (const float*)d_in[6];
    const float* f_w1   = (const float*)d_in[7];
    const float* f_b1   = (const float*)d_in[8];
    const float* f_w2   = (const float*)d_in[9];
    const float* f_b2   = (const float*)d_in[10];
    float* out = (float*)d_out;

    char* ws = (char*)d_ws;
    float* x      = (float*)(ws + 0);         //  64*64*26*4   = 425984
    float* u      = (float*)(ws + 425984);    //  64*64*256*4  = 4 MB
    float* v      = (float*)(ws + 4620288);   //  4 MB
    short* w2t    = (short*)(ws + 8814592);   //  256*256*2    = 128 KB
    float* part   = (float*)(ws + 8945664);   //  4096*256*4   = 4 MB
    float* pooled = (float*)(ws + 13139968);  //  64*256*4     = 64 KB

    k1_conv<<<256, 256, 0, stream>>>(image, conv_w, conv_b, x);
    k2_uv <<<8192, 256, 0, stream>>>(x, g_w1, g_b1, u, v);
    k2b_w2t<<<256, 256, 0, stream>>>(g_w2, w2t);
    k3_pairs<<<4096, 256, 0, stream>>>(u, v, w2t, g_b2, part);
    k4_pool<<<64, 256, 0, stream>>>(part, pooled);
    k5_head<<<64, 256, 0, stream>>>(pooled, f_w1, f_b1, f_w2, f_b2, out);
}

// Round 2
// 109.906 us; speedup vs baseline: 1.0098x; 1.0098x over previous
//
#include <hip/hip_runtime.h>
#include <hip/hip_bf16.h>
#include <stdint.h>

// RNDiscriminator: B=64, d^2=64 positions, 26 features, g: 52->256->256, f: 256->1
// h1[i,j] = relu(u'[j] + v[i]); dominant cost sum_ij relu(h1 @ W2 + b2) = 34.4 GF bf16.
// k3: block = (b, 4 i's): 256x256 h1 tile in LDS (128KB), 4 waves each 128x128 C-tile
// (acc = 256 VGPR), B-frags streamed from L2, fused relu+bias+colsum epilogue.

typedef float f32x4 __attribute__((ext_vector_type(4)));
typedef short short8 __attribute__((ext_vector_type(8)));

__device__ __forceinline__ short bf16_rne(float f) {
    union { float f; uint32_t u; } v; v.f = f;
    uint32_t u = v.u + 0x7FFFu + ((v.u >> 16) & 1u);
    return (short)(u >> 16);
}

__device__ __forceinline__ uint32_t cvt_pk_bf16(float lo, float hi) {
    uint32_t r;
    asm("v_cvt_pk_bf16_f32 %0, %1, %2" : "=v"(r) : "v"(lo), "v"(hi));
    return r;
}

// K1: conv 8x8 stride 8 + relu + coord channels -> x[b][pos][26]
__global__ void k1_conv(const float* __restrict__ img, const float* __restrict__ cw,
                        const float* __restrict__ cb, float* __restrict__ x) {
    int b = blockIdx.x >> 2;
    int q = blockIdx.x & 3;
    for (int idx = q * 416 + threadIdx.x; idx < q * 416 + 416; idx += 256) {
        int pos = idx / 26;
        int ch  = idx - pos * 26;
        int r = pos >> 3, c = pos & 7;
        float val;
        if (ch < 24) {
            float s = cb[ch];
            #pragma unroll
            for (int ci = 0; ci < 3; ++ci)
                #pragma unroll
                for (int kr = 0; kr < 8; ++kr) {
                    const float* ip = img + ((b * 3 + ci) * 64 + r * 8 + kr) * 64 + c * 8;
                    const float* wp = cw + ((ch * 3 + ci) * 8 + kr) * 8;
                    #pragma unroll
                    for (int kc = 0; kc < 8; ++kc) s += ip[kc] * wp[kc];
                }
            val = fmaxf(s, 0.f);
        } else if (ch == 24) {
            val = -1.f + (2.f / 7.f) * (float)c;
        } else {
            val = -1.f + (2.f / 7.f) * (float)r;
        }
        x[(b * 64 + pos) * 26 + ch] = val;
    }
}

// K2: u'[bj][c] = x[bj]@W1[:26] + b1  (uv=0);  v[bj][c] = x[bj]@W1[26:]  (uv=1)
__global__ void k2_uv(const float* __restrict__ x, const float* __restrict__ w1,
                      const float* __restrict__ b1, float* __restrict__ u,
                      float* __restrict__ v) {
    int bj = blockIdx.x & 4095;
    int uv = blockIdx.x >> 12;
    int c = threadIdx.x;
    const float* xr = x + bj * 26;
    const float* w  = w1 + uv * 26 * 256;
    float s = uv ? 0.f : b1[c];
    #pragma unroll
    for (int k = 0; k < 26; ++k) s += xr[k] * w[k * 256 + c];
    (uv ? v : u)[bj * 256 + c] = s;
}

// K2b: W2t[n][k] = bf16(W2[k][n])
__global__ void k2b_w2t(const float* __restrict__ w2, short* __restrict__ w2t) {
    int n = blockIdx.x, k = threadIdx.x;
    w2t[n * 256 + k] = bf16_rne(w2[k * 256 + n]);
}

// K3: block = (b, group of 4 i's). Stage 256x256 bf16 h1 tile (XOR-swizzled, 128KB),
// 4 waves in 2x2 each compute a 128x128 C-tile (acc 256 VGPR), B from L2,
// epilogue relu(C+b2) column-sum -> part[blk][wave][128]
__global__ __launch_bounds__(256, 1) void k3_pairs(
        const float* __restrict__ u, const float* __restrict__ v,
        const short* __restrict__ w2t, const float* __restrict__ b2,
        float* __restrict__ part) {
    __shared__ short h1s[256 * 256];   // 128 KB
    int blk = blockIdx.x;
    int b = blk >> 4, g = blk & 15, i0 = g * 4;
    int t = threadIdx.x;
    int lane = t & 63, wv = t >> 6;
    int wm = wv >> 1, wn = wv & 1;
    int lr = lane & 15, lg = lane >> 4;

    // ---- stage h1 = relu(u'[j] + v[i0+ii]) for 4 i's, bf16, swizzled ----
    {
        int tg = t >> 6;            // row subgroup = wave id
        int kq = (t & 63) * 4;      // 4-col slice per lane
        const float* vb = v + (b * 64 + i0) * 256 + kq;
        float4 vv0 = *(const float4*)(vb);
        float4 vv1 = *(const float4*)(vb + 256);
        float4 vv2 = *(const float4*)(vb + 512);
        float4 vv3 = *(const float4*)(vb + 768);
        #pragma unroll
        for (int rr = 0; rr < 16; ++rr) {
            int j = rr * 4 + tg;
            float4 uu = *(const float4*)(u + (b * 64 + j) * 256 + kq);
            #define STAGE_ONE(ii, VV)                                              \
            {                                                                      \
                float s0 = fmaxf(uu.x + VV.x, 0.f);                                \
                float s1 = fmaxf(uu.y + VV.y, 0.f);                                \
                float s2 = fmaxf(uu.z + VV.z, 0.f);                                \
                float s3 = fmaxf(uu.w + VV.w, 0.f);                                \
                int2 wpk; wpk.x = (int)cvt_pk_bf16(s0, s1);                        \
                wpk.y = (int)cvt_pk_bf16(s2, s3);                                  \
                int row = (ii) * 64 + j;                                           \
                int byte = (row * 512 + kq * 2) ^ ((row & 7) << 4);                \
                *(int2*)((char*)h1s + byte) = wpk;                                 \
            }
            STAGE_ONE(0, vv0)
            STAGE_ONE(1, vv1)
            STAGE_ONE(2, vv2)
            STAGE_ONE(3, vv3)
            #undef STAGE_ONE
        }
    }
    __syncthreads();

    // ---- GEMM: wave (wm,wn) computes rows [wm*128,+128) x cols [wn*128,+128) ----
    f32x4 acc[8][8];
    #pragma unroll
    for (int mi = 0; mi < 8; ++mi)
        #pragma unroll
        for (int ni = 0; ni < 8; ++ni) acc[mi][ni] = (f32x4){0.f, 0.f, 0.f, 0.f};

    const short* bp[8];
    #pragma unroll
    for (int ni = 0; ni < 8; ++ni)
        bp[ni] = w2t + (wn * 128 + ni * 16 + lr) * 256;

    #pragma unroll
    for (int ks = 0; ks < 8; ++ks) {
        int kb = ks * 32 + lg * 8;
        short8 Af[8], Bf[8];
        #pragma unroll
        for (int mi = 0; mi < 8; ++mi) {
            int row = wm * 128 + mi * 16 + lr;
            int byte = (row * 512 + kb * 2) ^ ((row & 7) << 4);
            Af[mi] = *(const short8*)((const char*)h1s + byte);
        }
        #pragma unroll
        for (int ni = 0; ni < 8; ++ni)
            Bf[ni] = *(const short8*)(bp[ni] + kb);
        #pragma unroll
        for (int mi = 0; mi < 8; ++mi)
            #pragma unroll
            for (int ni = 0; ni < 8; ++ni)
                acc[mi][ni] = __builtin_amdgcn_mfma_f32_16x16x32_bf16(
                    Af[mi], Bf[ni], acc[mi][ni], 0, 0, 0);
    }

    // ---- epilogue: relu(C + b2) column-sum over this wave's 128 rows ----
    float esum[8];
    #pragma unroll
    for (int ni = 0; ni < 8; ++ni) {
        float bias = b2[wn * 128 + ni * 16 + lr];
        float s = 0.f;
        #pragma unroll
        for (int mi = 0; mi < 8; ++mi)
            #pragma unroll
            for (int r = 0; r < 4; ++r)
                s += fmaxf(acc[mi][ni][r] + bias, 0.f);
        esum[ni] = s;
    }
    #pragma unroll
    for (int ni = 0; ni < 8; ++ni) {
        float s = esum[ni];
        s += __shfl_xor(s, 16);
        s += __shfl_xor(s, 32);
        if (lane < 16) part[(blk * 4 + wv) * 128 + ni * 16 + lr] = s;
    }
}

// K4: pooled[b][c] = sum over 16 groups x 2 wm of part[((b*16+g)*4 + wm*2+wn)*128 + (c&127)]
__global__ void k4_pool(const float* __restrict__ part, float* __restrict__ pooled) {
    int b = blockIdx.x, c = threadIdx.x;
    int wn = c >> 7, j = c & 127;
    float s = 0.f;
    for (int g = 0; g < 16; ++g) {
        const float* p = part + ((b * 16 + g) * 4) * 128;
        s += p[(wn) * 128 + j];          // wm=0
        s += p[(2 + wn) * 128 + j];      // wm=1
    }
    pooled[b * 256 + c] = s;
}

// K5: f-head
__global__ void k5_head(const float* __restrict__ pooled, const float* __restrict__ fw1,
                        const float* __restrict__ fb1, const float* __restrict__ fw2,
                        const float* __restrict__ fb2, float* __restrict__ out) {
    __shared__ float P[256];
    __shared__ float wsum[4];
    int b = blockIdx.x, t = threadIdx.x;
    P[t] = pooled[b * 256 + t];
    __syncthreads();
    float s = fb1[t];
    for (int k = 0; k < 256; ++k) s += P[k] * fw1[k * 256 + t];
    float h = fmaxf(s, 0.f);
    float p = h * fw2[t];
    #pragma unroll
    for (int off = 32; off >= 1; off >>= 1) p += __shfl_xor(p, off);
    if ((t & 63) == 0) wsum[t >> 6] = p;
    __syncthreads();
    if (t == 0) out[b] = wsum[0] + wsum[1] + wsum[2] + wsum[3] + fb2[0];
}

extern "C" void kernel_launch(void* const* d_in, const int* in_sizes, int n_in,
                              void* d_out, int out_size, void* d_ws, size_t ws_size,
                              hipStream_t stream) {
    const float* image  = (const float*)d_in[0];
    const float* conv_w = (const float*)d_in[1];
    const float* conv_b = (const float*)d_in[2];
    const float* g_w1   = (const float*)d_in[3];
    const float* g_b1   = (const float*)d_in[4];
    const float* g_w2   = (const float*)d_in[5];
    const float* g_b2   = (const float*)d_in[6];
    const float* f_w1   = (const float*)d_in[7];
    const float* f_b1   = (const float*)d_in[8];
    const float* f_w2   = (const float*)d_in[9];
    const float* f_b2   = (const float*)d_in[10];
    float* out = (float*)d_out;

    char* ws = (char*)d_ws;
    float* x      = (float*)(ws + 0);         //  64*64*26*4   = 425984
    float* u      = (float*)(ws + 425984);    //  4 MB
    float* v      = (float*)(ws + 4620288);   //  4 MB
    short* w2t    = (short*)(ws + 8814592);   //  128 KB
    float* part   = (float*)(ws + 8945664);   //  1024*4*128*4 = 2 MB
    float* pooled = (float*)(ws + 13139968);  //  64 KB

    k1_conv<<<256, 256, 0, stream>>>(image, conv_w, conv_b, x);
    k2_uv <<<8192, 256, 0, stream>>>(x, g_w1, g_b1, u, v);
    k2b_w2t<<<256, 256, 0, stream>>>(g_w2, w2t);
    k3_pairs<<<1024, 256, 0, stream>>>(u, v, w2t, g_b2, part);
    k4_pool<<<64, 256, 0, stream>>>(part, pooled);
    k5_head<<<64, 256, 0, stream>>>(pooled, f_w1, f_b1, f_w2, f_b2, out);
}